// Round 6
// baseline (175.638 us; speedup 1.0000x reference)
//
#include <hip/hip_runtime.h>
#include <float.h>
#include <math.h>

// Problem constants: query (8,512,64,64) f32, keys (2000,512) f32
constexpr int D_  = 512;
constexpr int HW_ = 4096;           // 64*64
constexpr int N_  = 32768;          // B*HW
constexpr int M_  = 2000;
constexpr int MP_ = 2048;           // padded key count

// fp8 stores RAW q; rnorm folded into the score at fold time (fr[r] = -2*rnorm).
// Numerics harness-verified R1-R5 (passed, absmax 8.0).

typedef int          i32x8  __attribute__((ext_vector_type(8)));
typedef float        f32x16 __attribute__((ext_vector_type(16)));
typedef unsigned int uu32x4 __attribute__((ext_vector_type(4)));
typedef unsigned int uu32x2 __attribute__((ext_vector_type(2)));

__device__ inline unsigned umn(unsigned a, unsigned b) { return a < b ? a : b; }
__device__ inline unsigned umx(unsigned a, unsigned b) { return a > b ? a : b; }

// single-instruction unsigned median-of-3 (VOP3, gfx9+)
__device__ inline unsigned med3u(unsigned a, unsigned b, unsigned c) {
    unsigned d;
    asm("v_med3_u32 %0, %1, %2, %3" : "=v"(d) : "v"(a), "v"(b), "v"(c));
    return d;
}

// pack 4 floats -> 4 OCP e4m3 bytes (v_cvt_pk_fp8_f32; OCP format on gfx950)
__device__ inline unsigned pk4f8(float a, float b, float c, float d) {
    int v = 0;
    v = __builtin_amdgcn_cvt_pk_fp8_f32(a, b, v, false);   // bytes 0-1
    v = __builtin_amdgcn_cvt_pk_fp8_f32(c, d, v, true);    // bytes 2-3
    return (unsigned)v;
}

// async global->LDS, 16 B per lane (dest = wave-uniform base + lane*16; src per-lane)
__device__ inline void gld16(void* lds, const void* g) {
    __builtin_amdgcn_global_load_lds(
        (const __attribute__((address_space(1))) unsigned int*)g,
        (__attribute__((address_space(3))) unsigned int*)lds,
        16, 0, 0);
}

// ---------------- kernel 1: SINGLE-PASS rnorm + fp8 A-fragment swizzle ----------------
// qsw8 holds raw q in e4m3, 32x32x64-A-fragment order:
// frag (pb32, kc64): lane L byte j  <->  A[m = pb*32 + (L&31)][k = kc*64 + (L>>5)*32 + j]
__global__ __launch_bounds__(256) void k_prep(const float* __restrict__ q,
                                              float* __restrict__ rnorm,
                                              unsigned char* __restrict__ qsw8) {
    __shared__ float  tile[64][65];
    __shared__ float4 part2[16][17];
    int t = threadIdx.x;
    int p0 = blockIdx.x * 64;                    // 64 | 4096 -> single batch per block
    const float* base = q + (size_t)(p0 / HW_) * (D_ * HW_) + (p0 % HW_);
    int pb0 = blockIdx.x * 2;                    // pb32 base (2 per block)

    float s0 = 0.f, s1 = 0.f, s2 = 0.f, s3 = 0.f;  // sumsq partials for px quad (t&15)*4
    for (int ct = 0; ct < 8; ++ct) {             // kc64 = ct
        if (ct) __syncthreads();                 // prev emit done before tile overwrite
#pragma unroll
        for (int i = 0; i < 4; ++i) {
            int sl = t + 256 * i;                // 1024 float4 slots: 64 ch-rows x 16
            int row = sl >> 4, p4 = (sl & 15) * 4;
            float4 v = *(const float4*)(base + (size_t)(ct * 64 + row) * HW_ + p4);
            s0 += v.x * v.x; s1 += v.y * v.y; s2 += v.z * v.z; s3 += v.w * v.w;
            tile[row][p4 + 0] = v.x; tile[row][p4 + 1] = v.y;
            tile[row][p4 + 2] = v.z; tile[row][p4 + 3] = v.w;
        }
        __syncthreads();
        {
            // 256 slots: 2 pb-frags x 64 lanes x 2 16B-halves
            int pbi = t >> 7, L = (t >> 1) & 63, hf = t & 1;
            int plx = pbi * 32 + (L & 31);
            int cl  = (L >> 5) * 32 + hf * 16;
            unsigned d[4];
#pragma unroll
            for (int w4 = 0; w4 < 4; ++w4)
                d[w4] = pk4f8(tile[cl + w4 * 4 + 0][plx],
                              tile[cl + w4 * 4 + 1][plx],
                              tile[cl + w4 * 4 + 2][plx],
                              tile[cl + w4 * 4 + 3][plx]);
            *(uu32x4*)(qsw8 + (((size_t)(pb0 + pbi) * 8 + ct) * 64 + L) * 32 + hf * 16)
                = (uu32x4){d[0], d[1], d[2], d[3]};
        }
    }
    // reduce sumsq: thread t held px quad (t&15)*4 over ch rows {t>>4 + 16i + 64ct}
    part2[t & 15][t >> 4] = make_float4(s0, s1, s2, s3);
    __syncthreads();
    if (t < 64) {
        float ss = 0.f;
#pragma unroll
        for (int g = 0; g < 16; ++g)
            ss += ((const float*)&part2[t >> 2][g])[t & 3];
        rnorm[p0 + t] = 1.0f / fmaxf(sqrtf(ss), 1e-12f);   // matches F.normalize eps
    }
}

// ---------------- kernel 2: fused |k|^2 + fp8 B-fragment swizzle ----------------
// frag (nb32, kc64): lane L byte j <-> B[k = kc*64 + (L>>5)*32 + j][n = nb*32 + (L&31)]
__global__ __launch_bounds__(256) void k_keys(const float* __restrict__ keys,
                                              float* __restrict__ kn,
                                              unsigned char* __restrict__ ksw8) {
    int wave = threadIdx.x >> 6;
    int lane = threadIdx.x & 63;
    int m = blockIdx.x * 4 + wave;               // grid 512 -> m in [0,2048)
    int kc = lane >> 3, sub = lane & 7;
    int kh = sub >> 2, bg = sub & 3;
    int c = kc * 64 + kh * 32 + bg * 8;          // 8 channels per lane, covers all 512
    float4 v0 = make_float4(0.f, 0.f, 0.f, 0.f);
    float4 v1 = make_float4(0.f, 0.f, 0.f, 0.f);
    if (m < M_) {
        const float* row = keys + (size_t)m * D_ + c;
        v0 = *(const float4*)(row);
        v1 = *(const float4*)(row + 4);
    }
    float s = v0.x * v0.x + v0.y * v0.y + v0.z * v0.z + v0.w * v0.w
            + v1.x * v1.x + v1.y * v1.y + v1.z * v1.z + v1.w * v1.w;
    for (int off = 32; off; off >>= 1) s += __shfl_down(s, off, 64);
    if (lane == 0) kn[m] = (m < M_) ? s : FLT_MAX;
    unsigned d0 = pk4f8(v0.x, v0.y, v0.z, v0.w);
    unsigned d1 = pk4f8(v1.x, v1.y, v1.z, v1.w);
    *(uu32x2*)(ksw8 + (((size_t)(m >> 5) * 8 + kc) * 64 + kh * 32 + (m & 31)) * 32 + bg * 8)
        = (uu32x2){d0, d1};
}

// insert packed (p,m) into sorted top-3 (p1<=p2<=p3); tie keeps existing (rescue decides)
__device__ inline void insert3u(unsigned& p1, unsigned& m1, unsigned& p2, unsigned& m2,
                                unsigned& p3, unsigned& m3, unsigned p, unsigned m) {
    if (p < p1)      { p3 = p2; m3 = m2; p2 = p1; m2 = m1; p1 = p; m1 = m; }
    else if (p < p2) { p3 = p2; m3 = m2; p2 = p; m2 = m; }
    else if (p < p3) { p3 = p; m3 = m; }
}

// ---------------- kernel 3: fp8 MX MFMA score GEMM, 32KB-LDS chunks, 3 blocks/CU ----------------
// R6: occupancy restructure. R3/R5 identical dur at 1-2 blocks/CU proved the kernel is
// per-wave-latency-bound; dur tracks resident waves (R2 3.2w=70us, R0 5.6w=63, R3/R5
// 5.8w=48.7). This round: 12 waves/CU.
//  - chunk = 32 keys (16 KB), double-buffer = 32 KB LDS (was 64 -> LDS no longer caps).
//  - staging via global_load_lds width-16 (no stg regs, no ds_writes; dest = linear
//    wave-uniform base + lane*16, src per-lane -- the guide's exact constraint).
//  - __launch_bounds__(256,3): 3 waves/SIMD -> regs capped 170; budget ~160
//    (a0-7=64, acc=16, pk=48, fr=16, temps).
//  - keys in 4 quarters, grid (256,4) = 1024 blocks -> 3 blocks co-resident per CU,
//    each SIMD gets 3 waves from 3 DIFFERENT blocks (independent phases).
// 10-bit id = key idx within quarter (decode m = yq*512 + id).
__global__ __launch_bounds__(256, 3) void k_mfma(const unsigned char* __restrict__ qsw8,
                                                 const unsigned char* __restrict__ ksw8,
                                                 const float* __restrict__ kn,
                                                 const float* __restrict__ rnorm,
                                                 uu32x4* __restrict__ best) {
    __shared__ __attribute__((aligned(16))) unsigned int bb[2][4096];  // 2 x 16 KiB
    int t = threadIdx.x;
    int lane = t & 63;
    int wv = __builtin_amdgcn_readfirstlane(t >> 6);   // wave 0..3 -> px rows wv*32..+32
    int colk = lane & 31, h = lane >> 5;
    int p0 = blockIdx.x * 128;
    int yq = blockIdx.y;                               // key quarter: yq*512

    // per-lane fold factors fr[r] = -2*rnorm[pixel(r,h)] (32x32 C/D row map)
    float fr[16];
#pragma unroll
    for (int r = 0; r < 16; ++r)
        fr[r] = -2.0f * rnorm[p0 + wv * 32 + (r & 3) + 8 * (r >> 2) + 4 * h];

    // preload ALL 8 A-frags of this wave's px group (16 KB -> 64 VGPR, reused 16x)
    const unsigned char* aq = qsw8 + ((size_t)(blockIdx.x * 4 + wv) * 8) * 2048 + lane * 32;
    i32x8 a0 = *(const i32x8*)(aq);
    i32x8 a1 = *(const i32x8*)(aq + 2048);
    i32x8 a2 = *(const i32x8*)(aq + 4096);
    i32x8 a3 = *(const i32x8*)(aq + 6144);
    i32x8 a4 = *(const i32x8*)(aq + 8192);
    i32x8 a5 = *(const i32x8*)(aq + 10240);
    i32x8 a6 = *(const i32x8*)(aq + 12288);
    i32x8 a7 = *(const i32x8*)(aq + 14336);

    const unsigned char* bsrc = ksw8 + (size_t)yq * 262144;   // quarter base (256 KB)

    // stage chunk 0 into bb[0]: 4 async 16B ops/thread, linear both sides
    {
        char* d = (char*)&bb[0][0];
#pragma unroll
        for (int r = 0; r < 4; ++r)
            gld16(d + r * 4096 + wv * 1024,
                  bsrc + r * 4096 + wv * 1024 + lane * 16);
    }
    __syncthreads();                             // compiler drains vmcnt before s_barrier

    unsigned pk1[16], pk2[16], pk3[16];
#pragma unroll
    for (int i = 0; i < 16; ++i) { pk1[i] = 0xFFFFFFFFu; pk2[i] = 0xFFFFFFFFu; pk3[i] = 0xFFFFFFFFu; }

    int scl = 0x7F7F7F7F;                        // e8m0 = 127 -> x1.0 in every byte/lane

#pragma unroll 1
    for (int c = 0; c < 16; ++c) {               // 16 chunks x 32 keys = 512-key quarter
        int cb = c & 1;
        // async-prefetch next chunk into the other buffer (no regs consumed)
        if (c < 15) {
            const unsigned char* s = bsrc + (size_t)(c + 1) * 16384;
            char* d = (char*)&bb[0][0] + (cb ^ 1) * 16384;
#pragma unroll
            for (int r = 0; r < 4; ++r)
                gld16(d + r * 4096 + wv * 1024,
                      s + r * 4096 + wv * 1024 + lane * 16);
        }
        float kn0 = kn[yq * 512 + c * 32 + colk];

        const char* bp = (const char*)&bb[0][0] + cb * 16384 + lane * 32;
        f32x16 acc;
#pragma unroll
        for (int r = 0; r < 16; ++r) acc[r] = 0.f;

#pragma unroll
        for (int kc = 0; kc < 8; ++kc) {
            i32x8 b0 = *(const i32x8*)(bp + (size_t)kc * 2048);
            i32x8 av = (kc == 0) ? a0 : (kc == 1) ? a1 : (kc == 2) ? a2 : (kc == 3) ? a3
                     : (kc == 4) ? a4 : (kc == 5) ? a5 : (kc == 6) ? a6 : a7;
            acc = __builtin_amdgcn_mfma_scale_f32_32x32x64_f8f6f4(
                av, b0, acc, 0, 0, 0, scl, 0, scl);
        }

        // fold this chunk's 16 scores (1 key column x 16 rows)
        unsigned id0 = (unsigned)(c * 32 + colk);
#pragma unroll
        for (int r = 0; r < 16; ++r) {
            float sc = fmaf(fr[r], acc[r], kn0);
            unsigned pz = (__float_as_uint(sc) & ~1023u) | id0;
            unsigned n2 = med3u(pk1[r], pk2[r], pz);
            unsigned n3 = med3u(pk2[r], pk3[r], pz);
            pk1[r] = umn(pk1[r], pz); pk2[r] = n2; pk3[r] = n3;
        }

        __syncthreads();                         // drains prefetch DMA + gates buffer swap
    }

    // ---- epilogue: packed-list butterfly over the 32 colk lanes; writers store top-3 ----
#pragma unroll
    for (int r = 0; r < 16; ++r) {
        unsigned a1w = pk1[r], a2w = pk2[r], a3w = pk3[r];
#pragma unroll
        for (int mask = 1; mask < 32; mask <<= 1) {
            unsigned b1 = (unsigned)__shfl_xor((int)a1w, mask, 64);
            unsigned b2 = (unsigned)__shfl_xor((int)a2w, mask, 64);
            unsigned b3 = (unsigned)__shfl_xor((int)a3w, mask, 64);
            unsigned x1 = umn(a1w, b1), y1 = umx(a1w, b1);
            unsigned x2 = umn(a2w, b2);
            unsigned z  = umn(a3w, b3);
            a1w = x1;
            a2w = umn(y1, x2);
            a3w = umn(umx(y1, x2), z);
        }
        if (colk == 0) {
            int pix = wv * 32 + (r & 3) + 8 * (r >> 2) + 4 * h;   // 32x32 C/D row map
            best[(size_t)yq * N_ + p0 + pix] = (uu32x4){a1w, a2w, a3w, 0u};
        }
    }
}

// ---------------- kernel 4: merge 12 cands -> approx-top-3, exact fp32 rescue + heatmap ----------------
// Block = 64 pixels x 4 c-groups (256 thr). Reads fp32 q (NOT fp8): rescue must be exact.
// (Verbatim the R4 merge-12 version -- harness-verified.)
__global__ __launch_bounds__(256) void k_heat(
    const float* __restrict__ q, const float* __restrict__ keys,
    const float* __restrict__ kn, const float* __restrict__ rnorm,
    const uu32x4* __restrict__ best, float* __restrict__ out)
{
    __shared__ float4 pA[64][5];                 // (d0,d1,d2,h0) x 4 cg (+1 pad)
    __shared__ float4 pB[64][5];                 // (h1,h2,-,-)
    int t = threadIdx.x;
    int pl = t & 63, cg = t >> 6;
    int p0 = blockIdx.x * 64;
    int p = p0 + pl;
    const float* qb = q + (size_t)(p / HW_) * (D_ * HW_) + (p % HW_);

    // merge the 4 quarters' packed top-3 lists (u32 compare = score-major)
    uu32x4 c0 = best[p];
    uu32x4 c1 = best[N_ + p];
    uu32x4 c2 = best[2 * (size_t)N_ + p];
    uu32x4 c3 = best[3 * (size_t)N_ + p];
    unsigned p1 = c0[0], p2 = c0[1], p3 = c0[2];
    unsigned m1 = p1 & 1023u, m2 = p2 & 1023u, m3 = p3 & 1023u;
    insert3u(p1, m1, p2, m2, p3, m3, c1[0],  512u + (c1[0] & 1023u));
    insert3u(p1, m1, p2, m2, p3, m3, c1[1],  512u + (c1[1] & 1023u));
    insert3u(p1, m1, p2, m2, p3, m3, c1[2],  512u + (c1[2] & 1023u));
    insert3u(p1, m1, p2, m2, p3, m3, c2[0], 1024u + (c2[0] & 1023u));
    insert3u(p1, m1, p2, m2, p3, m3, c2[1], 1024u + (c2[1] & 1023u));
    insert3u(p1, m1, p2, m2, p3, m3, c2[2], 1024u + (c2[2] & 1023u));
    insert3u(p1, m1, p2, m2, p3, m3, c3[0], 1536u + (c3[0] & 1023u));
    insert3u(p1, m1, p2, m2, p3, m3, c3[1], 1536u + (c3[1] & 1023u));
    insert3u(p1, m1, p2, m2, p3, m3, c3[2], 1536u + (c3[2] & 1023u));
    unsigned ci[3] = { m1, m2, m3 };

    float rn = rnorm[p];
    const float* kp0 = keys + (size_t)ci[0] * D_;
    const float* kp1 = keys + (size_t)ci[1] * D_;
    const float* kp2 = keys + (size_t)ci[2] * D_;
    float d0 = 0.f, d1 = 0.f, d2 = 0.f, h0 = 0.f, h1 = 0.f, h2 = 0.f;
    for (int c = cg * 128; c < cg * 128 + 128; c += 4) {
        float qv[4];
#pragma unroll
        for (int j = 0; j < 4; ++j) qv[j] = qb[(size_t)(c + j) * HW_] * rn;  // coalesced
        float4 k0 = *(const float4*)(kp0 + c);
        float4 k1 = *(const float4*)(kp1 + c);
        float4 k2 = *(const float4*)(kp2 + c);
        d0 += qv[0] * k0.x + qv[1] * k0.y + qv[2] * k0.z + qv[3] * k0.w;
        d1 += qv[0] * k1.x + qv[1] * k1.y + qv[2] * k1.z + qv[3] * k1.w;
        d2 += qv[0] * k2.x + qv[1] * k2.y + qv[2] * k2.z + qv[3] * k2.w;
#pragma unroll
        for (int j = 0; j < 4; ++j) {
            float kj0 = ((const float*)&k0)[j], kj1 = ((const float*)&k1)[j], kj2 = ((const float*)&k2)[j];
            float a = qv[j] - kj0, b = qv[j] - kj1, cc = qv[j] - kj2;
            float a2 = a * a, b2 = b * b, c2 = cc * cc;
            h0 += a2 * a2; h1 += b2 * b2; h2 += c2 * c2;
        }
    }
    pA[pl][cg] = make_float4(d0, d1, d2, h0);
    pB[pl][cg] = make_float4(h1, h2, 0.f, 0.f);
    __syncthreads();
    if (t < 64) {                                // cg==0 thread for pixel t holds ci[]
        float D0 = 0.f, D1 = 0.f, D2 = 0.f, H0 = 0.f, H1 = 0.f, H2 = 0.f;
#pragma unroll
        for (int g = 0; g < 4; ++g) {
            float4 a = pA[t][g], b = pB[t][g];
            D0 += a.x; D1 += a.y; D2 += a.z; H0 += a.w; H1 += b.x; H2 += b.y;
        }
        float sA = kn[ci[0]] - 2.0f * D0;
        float sB = kn[ci[1]] - 2.0f * D1;
        float sC = kn[ci[2]] - 2.0f * D2;
        // exact argmin among candidates; tie -> smaller index
        float bs = sA; unsigned bi = ci[0]; float bh = H0;
        if (sB < bs || (sB == bs && ci[1] < bi)) { bs = sB; bi = ci[1]; bh = H1; }
        if (sC < bs || (sC == bs && ci[2] < bi)) { bs = sC; bi = ci[2]; bh = H2; }
        out[p0 + t] = bh;
    }
}

extern "C" void kernel_launch(void* const* d_in, const int* in_sizes, int n_in,
                              void* d_out, int out_size, void* d_ws, size_t ws_size,
                              hipStream_t stream) {
    const float* query = (const float*)d_in[0];   // (8,512,64,64) f32
    const float* keys  = (const float*)d_in[1];   // (2000,512) f32
    float* out = (float*)d_out;                   // 32768 f32

    // workspace layout (~20 MB):
    char* ws = (char*)d_ws;
    unsigned char* qsw8 = (unsigned char*)ws;                        // N*D fp8   = 16.8 MB
    unsigned char* ksw8 = qsw8 + (size_t)N_ * D_;                    // MP*D fp8  = 1 MB
    float*  rnorm  = (float*)(ksw8 + (size_t)MP_ * D_);
    float*  kn     = rnorm + N_;
    uu32x4* best   = (uu32x4*)(kn + MP_);                            // 4*N uu32x4 = 2 MB

    k_keys<<<MP_ / 4,           256, 0, stream>>>(keys, kn, ksw8);
    k_prep<<<N_ / 64,           256, 0, stream>>>(query, rnorm, qsw8);
    k_mfma<<<dim3(N_ / 128, 4), 256, 0, stream>>>(qsw8, ksw8, kn, rnorm, best);
    k_heat<<<N_ / 64,           256, 0, stream>>>(query, keys, kn, rnorm, best, out);
}

// Round 7
// 159.841 us; speedup vs baseline: 1.0988x; 1.0988x over previous
//
#include <hip/hip_runtime.h>
#include <float.h>
#include <math.h>

// Problem constants: query (8,512,64,64) f32, keys (2000,512) f32
constexpr int D_  = 512;
constexpr int HW_ = 4096;           // 64*64
constexpr int N_  = 32768;          // B*HW
constexpr int M_  = 2000;
constexpr int MP_ = 2048;           // padded key count

// fp8 stores RAW q; rnorm folded into the score at fold time (fr[r] = -2*rnorm).
// Numerics harness-verified R1-R6 (passed, absmax 8.0).

typedef int          i32x8  __attribute__((ext_vector_type(8)));
typedef float        f32x16 __attribute__((ext_vector_type(16)));
typedef unsigned int uu32x4 __attribute__((ext_vector_type(4)));
typedef unsigned int uu32x2 __attribute__((ext_vector_type(2)));

__device__ inline unsigned umn(unsigned a, unsigned b) { return a < b ? a : b; }
__device__ inline unsigned umx(unsigned a, unsigned b) { return a > b ? a : b; }

// single-instruction unsigned median-of-3 (VOP3, gfx9+)
__device__ inline unsigned med3u(unsigned a, unsigned b, unsigned c) {
    unsigned d;
    asm("v_med3_u32 %0, %1, %2, %3" : "=v"(d) : "v"(a), "v"(b), "v"(c));
    return d;
}

// pack 4 floats -> 4 OCP e4m3 bytes (v_cvt_pk_fp8_f32; OCP format on gfx950)
__device__ inline unsigned pk4f8(float a, float b, float c, float d) {
    int v = 0;
    v = __builtin_amdgcn_cvt_pk_fp8_f32(a, b, v, false);   // bytes 0-1
    v = __builtin_amdgcn_cvt_pk_fp8_f32(c, d, v, true);    // bytes 2-3
    return (unsigned)v;
}

// async global->LDS, 16 B per lane (dest = wave-uniform base + lane*16; src per-lane)
__device__ inline void gld16(void* lds, const void* g) {
    __builtin_amdgcn_global_load_lds(
        (const __attribute__((address_space(1))) unsigned int*)g,
        (__attribute__((address_space(3))) unsigned int*)lds,
        16, 0, 0);
}

// ---------------- kernel 1: SINGLE-PASS rnorm + fp8 A-fragment swizzle ----------------
// qsw8 holds raw q in e4m3, 32x32x64-A-fragment order:
// frag (pb32, kc64): lane L byte j  <->  A[m = pb*32 + (L&31)][k = kc*64 + (L>>5)*32 + j]
__global__ __launch_bounds__(256) void k_prep(const float* __restrict__ q,
                                              float* __restrict__ rnorm,
                                              unsigned char* __restrict__ qsw8) {
    __shared__ float  tile[64][65];
    __shared__ float4 part2[16][17];
    int t = threadIdx.x;
    int p0 = blockIdx.x * 64;                    // 64 | 4096 -> single batch per block
    const float* base = q + (size_t)(p0 / HW_) * (D_ * HW_) + (p0 % HW_);
    int pb0 = blockIdx.x * 2;                    // pb32 base (2 per block)

    float s0 = 0.f, s1 = 0.f, s2 = 0.f, s3 = 0.f;  // sumsq partials for px quad (t&15)*4
    for (int ct = 0; ct < 8; ++ct) {             // kc64 = ct
        if (ct) __syncthreads();                 // prev emit done before tile overwrite
#pragma unroll
        for (int i = 0; i < 4; ++i) {
            int sl = t + 256 * i;                // 1024 float4 slots: 64 ch-rows x 16
            int row = sl >> 4, p4 = (sl & 15) * 4;
            float4 v = *(const float4*)(base + (size_t)(ct * 64 + row) * HW_ + p4);
            s0 += v.x * v.x; s1 += v.y * v.y; s2 += v.z * v.z; s3 += v.w * v.w;
            tile[row][p4 + 0] = v.x; tile[row][p4 + 1] = v.y;
            tile[row][p4 + 2] = v.z; tile[row][p4 + 3] = v.w;
        }
        __syncthreads();
        {
            // 256 slots: 2 pb-frags x 64 lanes x 2 16B-halves
            int pbi = t >> 7, L = (t >> 1) & 63, hf = t & 1;
            int plx = pbi * 32 + (L & 31);
            int cl  = (L >> 5) * 32 + hf * 16;
            unsigned d[4];
#pragma unroll
            for (int w4 = 0; w4 < 4; ++w4)
                d[w4] = pk4f8(tile[cl + w4 * 4 + 0][plx],
                              tile[cl + w4 * 4 + 1][plx],
                              tile[cl + w4 * 4 + 2][plx],
                              tile[cl + w4 * 4 + 3][plx]);
            *(uu32x4*)(qsw8 + (((size_t)(pb0 + pbi) * 8 + ct) * 64 + L) * 32 + hf * 16)
                = (uu32x4){d[0], d[1], d[2], d[3]};
        }
    }
    // reduce sumsq: thread t held px quad (t&15)*4 over ch rows {t>>4 + 16i + 64ct}
    part2[t & 15][t >> 4] = make_float4(s0, s1, s2, s3);
    __syncthreads();
    if (t < 64) {
        float ss = 0.f;
#pragma unroll
        for (int g = 0; g < 16; ++g)
            ss += ((const float*)&part2[t >> 2][g])[t & 3];
        rnorm[p0 + t] = 1.0f / fmaxf(sqrtf(ss), 1e-12f);   // matches F.normalize eps
    }
}

// ---------------- kernel 2: fused |k|^2 + fp8 B-fragment swizzle ----------------
// frag (nb32, kc64): lane L byte j <-> B[k = kc*64 + (L>>5)*32 + j][n = nb*32 + (L&31)]
__global__ __launch_bounds__(256) void k_keys(const float* __restrict__ keys,
                                              float* __restrict__ kn,
                                              unsigned char* __restrict__ ksw8) {
    int wave = threadIdx.x >> 6;
    int lane = threadIdx.x & 63;
    int m = blockIdx.x * 4 + wave;               // grid 512 -> m in [0,2048)
    int kc = lane >> 3, sub = lane & 7;
    int kh = sub >> 2, bg = sub & 3;
    int c = kc * 64 + kh * 32 + bg * 8;          // 8 channels per lane, covers all 512
    float4 v0 = make_float4(0.f, 0.f, 0.f, 0.f);
    float4 v1 = make_float4(0.f, 0.f, 0.f, 0.f);
    if (m < M_) {
        const float* row = keys + (size_t)m * D_ + c;
        v0 = *(const float4*)(row);
        v1 = *(const float4*)(row + 4);
    }
    float s = v0.x * v0.x + v0.y * v0.y + v0.z * v0.z + v0.w * v0.w
            + v1.x * v1.x + v1.y * v1.y + v1.z * v1.z + v1.w * v1.w;
    for (int off = 32; off; off >>= 1) s += __shfl_down(s, off, 64);
    if (lane == 0) kn[m] = (m < M_) ? s : FLT_MAX;
    unsigned d0 = pk4f8(v0.x, v0.y, v0.z, v0.w);
    unsigned d1 = pk4f8(v1.x, v1.y, v1.z, v1.w);
    *(uu32x2*)(ksw8 + (((size_t)(m >> 5) * 8 + kc) * 64 + kh * 32 + (m & 31)) * 32 + bg * 8)
        = (uu32x2){d0, d1};
}

// insert (t,j) into sorted top-3 (s1<=s2<=s3) with index tie-break
__device__ inline void insert3(float& s1, unsigned& i1, float& s2, unsigned& i2,
                               float& s3, unsigned& i3, float t, unsigned j) {
    if (t < s1 || (t == s1 && j < i1))      { s3 = s2; i3 = i2; s2 = s1; i2 = i1; s1 = t; i1 = j; }
    else if (t < s2 || (t == s2 && j < i2)) { s3 = s2; i3 = i2; s2 = t; i2 = j; }
    else if (t < s3 || (t == s3 && j < i3)) { s3 = t; i3 = j; }
}

// ---------------- kernel 3: fp8 MX MFMA score GEMM, LDS-staged B, 4 MFMA chains ----------------
// R7: ILP restructure. R6 proved dur tracks (resident waves x independent MFMA chains):
// R5 2x6=12 -> 48.7us, R6 1x7=7 -> 58.4us. Occupancy is pinned ~2 blocks/CU no matter
// the LDS size (R3=R5=R6), so this round multiplies CHAINS: K-split accumulators
// (acc0a=kc0-3, acc0b=kc4-7 per key column; x2 columns = 4 independent chains, depth 4).
// Folded as acc_a + acc_b (1 extra v_add per score). Staging via global_load_lds
// (R6-verified; frees the 32 stg VGPRs to pay for the extra 32 acc AGPRs).
// Skeleton = R5 (64-key chunks, 64KB dbuf, grid (256,2), best12/best3 epilogue).
// 10-bit id = local key index within the yb half (decode m = yb*1024 + id).
__global__ __launch_bounds__(256, 2) void k_mfma(const unsigned char* __restrict__ qsw8,
                                                 const unsigned char* __restrict__ ksw8,
                                                 const float* __restrict__ kn,
                                                 const float* __restrict__ rnorm,
                                                 float4* __restrict__ best12,
                                                 float2* __restrict__ best3) {
    __shared__ __attribute__((aligned(16))) unsigned int bb[2][8192];  // 2 x 32 KiB
    int t = threadIdx.x;
    int lane = t & 63;
    int wv = __builtin_amdgcn_readfirstlane(t >> 6);   // wave 0..3 -> px rows wv*32..+32
    int colk = lane & 31, h = lane >> 5;
    int p0 = blockIdx.x * 128;
    int yb = blockIdx.y;                               // key half: yb*1024

    // per-lane fold factors fr[r] = -2*rnorm[pixel(r,h)] (32x32 C/D row map)
    float fr[16];
#pragma unroll
    for (int r = 0; r < 16; ++r)
        fr[r] = -2.0f * rnorm[p0 + wv * 32 + (r & 3) + 8 * (r >> 2) + 4 * h];

    // preload ALL 8 A-frags of this wave's px group (16 KB -> 64 regs, reused 16x)
    const unsigned char* aq = qsw8 + ((size_t)(blockIdx.x * 4 + wv) * 8) * 2048 + lane * 32;
    i32x8 a0 = *(const i32x8*)(aq);
    i32x8 a1 = *(const i32x8*)(aq + 2048);
    i32x8 a2 = *(const i32x8*)(aq + 4096);
    i32x8 a3 = *(const i32x8*)(aq + 6144);
    i32x8 a4 = *(const i32x8*)(aq + 8192);
    i32x8 a5 = *(const i32x8*)(aq + 10240);
    i32x8 a6 = *(const i32x8*)(aq + 12288);
    i32x8 a7 = *(const i32x8*)(aq + 14336);

    const unsigned char* bsrc = ksw8 + ((size_t)yb * 32 * 8) * 2048;   // half base (512 KB)
    char* lb = (char*)&bb[0][0];

    // stage chunk 0 into bb[0]: 8 async 16B DMA ops/thread, linear both sides
#pragma unroll
    for (int r = 0; r < 8; ++r)
        gld16(lb + r * 4096 + wv * 1024,
              bsrc + r * 4096 + wv * 1024 + lane * 16);
    __syncthreads();                             // compiler drains vmcnt before s_barrier

    unsigned pk1[16], pk2[16], pk3[16];
#pragma unroll
    for (int i = 0; i < 16; ++i) { pk1[i] = 0xFFFFFFFFu; pk2[i] = 0xFFFFFFFFu; pk3[i] = 0xFFFFFFFFu; }

    int scl = 0x7F7F7F7F;                        // e8m0 = 127 -> x1.0 in every byte/lane

#pragma unroll 1
    for (int c = 0; c < 16; ++c) {               // 16 chunks x 64 keys = 1024-key half
        int cb = c & 1;
        // async-prefetch next chunk into the other buffer (no regs consumed)
        if (c < 15) {
            const unsigned char* s = bsrc + (size_t)(c + 1) * 32768;
            char* d = lb + (cb ^ 1) * 32768;
#pragma unroll
            for (int r = 0; r < 8; ++r)
                gld16(d + r * 4096 + wv * 1024,
                      s + r * 4096 + wv * 1024 + lane * 16);
        }
        float kn0 = kn[yb * 1024 + c * 64 + colk];
        float kn1 = kn[yb * 1024 + c * 64 + 32 + colk];

        const char* bp = lb + cb * 32768 + lane * 32;
        f32x16 acc0a, acc0b, acc1a, acc1b;       // 4 independent chains, depth 4
#pragma unroll
        for (int r = 0; r < 16; ++r) { acc0a[r] = 0.f; acc0b[r] = 0.f; acc1a[r] = 0.f; acc1b[r] = 0.f; }

#pragma unroll
        for (int kc = 0; kc < 4; ++kc) {
            i32x8 b0 = *(const i32x8*)(bp + (size_t)kc * 2048);          // col 0
            i32x8 b1 = *(const i32x8*)(bp + (size_t)(8 + kc) * 2048);    // col 1
            i32x8 av = (kc == 0) ? a0 : (kc == 1) ? a1 : (kc == 2) ? a2 : a3;
            acc0a = __builtin_amdgcn_mfma_scale_f32_32x32x64_f8f6f4(
                av, b0, acc0a, 0, 0, 0, scl, 0, scl);
            acc1a = __builtin_amdgcn_mfma_scale_f32_32x32x64_f8f6f4(
                av, b1, acc1a, 0, 0, 0, scl, 0, scl);
        }
#pragma unroll
        for (int kc = 4; kc < 8; ++kc) {
            i32x8 b0 = *(const i32x8*)(bp + (size_t)kc * 2048);
            i32x8 b1 = *(const i32x8*)(bp + (size_t)(8 + kc) * 2048);
            i32x8 av = (kc == 4) ? a4 : (kc == 5) ? a5 : (kc == 6) ? a6 : a7;
            acc0b = __builtin_amdgcn_mfma_scale_f32_32x32x64_f8f6f4(
                av, b0, acc0b, 0, 0, 0, scl, 0, scl);
            acc1b = __builtin_amdgcn_mfma_scale_f32_32x32x64_f8f6f4(
                av, b1, acc1b, 0, 0, 0, scl, 0, scl);
        }

        // fold this chunk's 32 scores (2 key columns x 16 rows); acc = a-half + b-half
        unsigned id0 = ((unsigned)(c * 2) << 5) | (unsigned)colk;
        unsigned id1 = id0 + 32;
#pragma unroll
        for (int r = 0; r < 16; ++r) {
            float sc0 = fmaf(fr[r], acc0a[r] + acc0b[r], kn0);
            unsigned pz = (__float_as_uint(sc0) & ~1023u) | id0;
            unsigned n2 = med3u(pk1[r], pk2[r], pz);
            unsigned n3 = med3u(pk2[r], pk3[r], pz);
            pk1[r] = umn(pk1[r], pz); pk2[r] = n2; pk3[r] = n3;
            float sc1 = fmaf(fr[r], acc1a[r] + acc1b[r], kn1);
            pz = (__float_as_uint(sc1) & ~1023u) | id1;
            n2 = med3u(pk1[r], pk2[r], pz);
            n3 = med3u(pk2[r], pk3[r], pz);
            pk1[r] = umn(pk1[r], pz); pk2[r] = n2; pk3[r] = n3;
        }

        __syncthreads();                         // drains own DMA (vmcnt0) + gates swap
    }

    // ---- epilogue: packed-list butterfly over the 32 colk lanes; writers store top-3 ----
#pragma unroll
    for (int r = 0; r < 16; ++r) {
        unsigned a1w = pk1[r], a2w = pk2[r], a3w = pk3[r];
#pragma unroll
        for (int mask = 1; mask < 32; mask <<= 1) {
            unsigned b1 = (unsigned)__shfl_xor((int)a1w, mask, 64);
            unsigned b2 = (unsigned)__shfl_xor((int)a2w, mask, 64);
            unsigned b3 = (unsigned)__shfl_xor((int)a3w, mask, 64);
            unsigned x1 = umn(a1w, b1), y1 = umx(a1w, b1);
            unsigned x2 = umn(a2w, b2);
            unsigned z  = umn(a3w, b3);
            a1w = x1;
            a2w = umn(y1, x2);
            a3w = umn(umx(y1, x2), z);
        }
        if (colk == 0) {
            int pix = wv * 32 + (r & 3) + 8 * (r >> 2) + 4 * h;   // 32x32 C/D row map
            unsigned l1 = a1w & 1023u, l2 = a2w & 1023u, l3 = a3w & 1023u;
            unsigned m1 = (unsigned)(yb * 1024) + l1;            // id IS the local index
            unsigned m2 = (unsigned)(yb * 1024) + l2;
            unsigned m3 = (unsigned)(yb * 1024) + l3;
            size_t o = (size_t)yb * N_ + p0 + pix;
            best12[o] = make_float4(__uint_as_float(a1w & ~1023u), __uint_as_float(m1),
                                    __uint_as_float(a2w & ~1023u), __uint_as_float(m2));
            best3[o]  = make_float2(__uint_as_float(a3w & ~1023u), __uint_as_float(m3));
        }
    }
}

// ---------------- kernel 4: merge 6 cands -> approx-top-3, exact fp32 rescue + heatmap ----------------
// Block = 64 pixels x 4 c-groups (256 thr). Reads fp32 q (NOT fp8): rescue must be exact.
__global__ __launch_bounds__(256) void k_heat(
    const float* __restrict__ q, const float* __restrict__ keys,
    const float* __restrict__ kn, const float* __restrict__ rnorm,
    const float4* __restrict__ best12, const float2* __restrict__ best3,
    float* __restrict__ out)
{
    __shared__ float4 pA[64][5];                 // (d0,d1,d2,h0) x 4 cg (+1 pad)
    __shared__ float4 pB[64][5];                 // (h1,h2,-,-)
    int t = threadIdx.x;
    int pl = t & 63, cg = t >> 6;
    int p0 = blockIdx.x * 64;
    int p = p0 + pl;
    const float* qb = q + (size_t)(p / HW_) * (D_ * HW_) + (p % HW_);

    // gather the 2 halves' top-3 lists, merge to approx-top-3 (redundant per cg)
    float4 eA = best12[p];          float2 eA3 = best3[p];
    float4 eB = best12[N_ + p];     float2 eB3 = best3[N_ + p];
    float s1 = eA.x, s2 = eA.z, s3 = eA3.x;
    unsigned i1 = __float_as_uint(eA.y), i2 = __float_as_uint(eA.w), i3 = __float_as_uint(eA3.y);
    insert3(s1, i1, s2, i2, s3, i3, eB.x,  __float_as_uint(eB.y));
    insert3(s1, i1, s2, i2, s3, i3, eB.z,  __float_as_uint(eB.w));
    insert3(s1, i1, s2, i2, s3, i3, eB3.x, __float_as_uint(eB3.y));
    unsigned ci[3] = { i1, i2, i3 };

    float rn = rnorm[p];
    const float* kp0 = keys + (size_t)ci[0] * D_;
    const float* kp1 = keys + (size_t)ci[1] * D_;
    const float* kp2 = keys + (size_t)ci[2] * D_;
    float d0 = 0.f, d1 = 0.f, d2 = 0.f, h0 = 0.f, h1 = 0.f, h2 = 0.f;
    for (int c = cg * 128; c < cg * 128 + 128; c += 4) {
        float qv[4];
#pragma unroll
        for (int j = 0; j < 4; ++j) qv[j] = qb[(size_t)(c + j) * HW_] * rn;  // coalesced
        float4 k0 = *(const float4*)(kp0 + c);
        float4 k1 = *(const float4*)(kp1 + c);
        float4 k2 = *(const float4*)(kp2 + c);
        d0 += qv[0] * k0.x + qv[1] * k0.y + qv[2] * k0.z + qv[3] * k0.w;
        d1 += qv[0] * k1.x + qv[1] * k1.y + qv[2] * k1.z + qv[3] * k1.w;
        d2 += qv[0] * k2.x + qv[1] * k2.y + qv[2] * k2.z + qv[3] * k2.w;
#pragma unroll
        for (int j = 0; j < 4; ++j) {
            float kj0 = ((const float*)&k0)[j], kj1 = ((const float*)&k1)[j], kj2 = ((const float*)&k2)[j];
            float a = qv[j] - kj0, b = qv[j] - kj1, cc = qv[j] - kj2;
            float a2 = a * a, b2 = b * b, c2 = cc * cc;
            h0 += a2 * a2; h1 += b2 * b2; h2 += c2 * c2;
        }
    }
    pA[pl][cg] = make_float4(d0, d1, d2, h0);
    pB[pl][cg] = make_float4(h1, h2, 0.f, 0.f);
    __syncthreads();
    if (t < 64) {                                // cg==0 thread for pixel t holds ci[]
        float D0 = 0.f, D1 = 0.f, D2 = 0.f, H0 = 0.f, H1 = 0.f, H2 = 0.f;
#pragma unroll
        for (int g = 0; g < 4; ++g) {
            float4 a = pA[t][g], b = pB[t][g];
            D0 += a.x; D1 += a.y; D2 += a.z; H0 += a.w; H1 += b.x; H2 += b.y;
        }
        float sA = kn[ci[0]] - 2.0f * D0;
        float sB = kn[ci[1]] - 2.0f * D1;
        float sC = kn[ci[2]] - 2.0f * D2;
        // exact argmin among candidates; tie -> smaller index
        float bs = sA; unsigned bi = ci[0]; float bh = H0;
        if (sB < bs || (sB == bs && ci[1] < bi)) { bs = sB; bi = ci[1]; bh = H1; }
        if (sC < bs || (sC == bs && ci[2] < bi)) { bs = sC; bi = ci[2]; bh = H2; }
        out[p0 + t] = bh;
    }
}

extern "C" void kernel_launch(void* const* d_in, const int* in_sizes, int n_in,
                              void* d_out, int out_size, void* d_ws, size_t ws_size,
                              hipStream_t stream) {
    const float* query = (const float*)d_in[0];   // (8,512,64,64) f32
    const float* keys  = (const float*)d_in[1];   // (2000,512) f32
    float* out = (float*)d_out;                   // 32768 f32

    // workspace layout (~20 MB):
    char* ws = (char*)d_ws;
    unsigned char* qsw8 = (unsigned char*)ws;                        // N*D fp8   = 16.8 MB
    unsigned char* ksw8 = qsw8 + (size_t)N_ * D_;                    // MP*D fp8  = 1 MB
    float*  rnorm  = (float*)(ksw8 + (size_t)MP_ * D_);
    float*  kn     = rnorm + N_;
    float4* best12 = (float4*)(kn + MP_);                            // 2*N float4 = 1 MB
    float2* best3  = (float2*)(best12 + 2 * (size_t)N_);             // 2*N float2 = 0.5 MB

    k_keys<<<MP_ / 4,           256, 0, stream>>>(keys, kn, ksw8);
    k_prep<<<N_ / 64,           256, 0, stream>>>(query, rnorm, qsw8);
    k_mfma<<<dim3(N_ / 128, 2), 256, 0, stream>>>(qsw8, ksw8, kn, rnorm, best12, best3);
    k_heat<<<N_ / 64,           256, 0, stream>>>(query, keys, kn, rnorm, best12, best3, out);
}